// Round 13
// baseline (2447.666 us; speedup 1.0000x reference)
//
#include <hip/hip_runtime.h>
#include <math.h>

#define Bq 4
#define Mq 500
#define Nq 500
#define Cq 91
#define NPHASE 6
#define AUC_UNDERPAY 1e-6f

// ---------------------------------------------------------------------------
// Phase 1: cost[b,i,j] = 0.5*||center2_i - center1_j||_2
//                      + 0.5*max_c |sigmoid(l2[i,c]) - sigmoid(l1[j,c])|
// ---------------------------------------------------------------------------
__device__ __forceinline__ float sigmoidf_(float x) {
    return 1.0f / (1.0f + expf(-x));
}

__global__ __launch_bounds__(256) void cost_kernel(
    const float* __restrict__ p1_boxes, const float* __restrict__ p1_logits,
    const float* __restrict__ p2_boxes, const float* __restrict__ p2_logits,
    float* __restrict__ cost)
{
    __shared__ float s2t[16][Cq + 1];   // stride 92 -> 2-way bank alias (free)
    __shared__ float s1t[16][Cq + 1];
    __shared__ float b2x[16], b2y[16], b1x[16], b1y[16];
    const int b  = blockIdx.z;
    const int i0 = blockIdx.y * 16;
    const int j0 = blockIdx.x * 16;
    const int tid = threadIdx.x;

    for (int t = tid; t < 16 * Cq; t += 256) {
        const int r = t / Cq, c = t - r * Cq;
        const int i = min(i0 + r, Mq - 1);
        const int j = min(j0 + r, Nq - 1);
        s2t[r][c] = sigmoidf_(p2_logits[((size_t)b * Mq + i) * Cq + c]);
        s1t[r][c] = sigmoidf_(p1_logits[((size_t)b * Nq + j) * Cq + c]);
    }
    if (tid < 16) {
        const int i = min(i0 + tid, Mq - 1);
        const int j = min(j0 + tid, Nq - 1);
        b2x[tid] = p2_boxes[((size_t)b * Mq + i) * 4 + 0];
        b2y[tid] = p2_boxes[((size_t)b * Mq + i) * 4 + 1];
        b1x[tid] = p1_boxes[((size_t)b * Nq + j) * 4 + 0];
        b1y[tid] = p1_boxes[((size_t)b * Nq + j) * 4 + 1];
    }
    __syncthreads();

    const int ty = tid >> 4, tx = tid & 15;
    const int i = i0 + ty, j = j0 + tx;
    if (i < Mq && j < Nq) {
        float mx = 0.0f;
        #pragma unroll 7
        for (int c = 0; c < Cq; ++c)
            mx = fmaxf(mx, fabsf(s2t[ty][c] - s1t[tx][c]));
        const float dx = b2x[ty] - b1x[tx];
        const float dy = b2y[ty] - b1y[tx];
        const float cd = sqrtf(dx * dx + dy * dy);
        cost[((size_t)b * Mq + i) * Nq + j] = 0.5f * cd + 0.5f * mx;
    }
}

// ---------------------------------------------------------------------------
// Phase 1.5: column reduction. v0[b][j] = min_i cost[b][i][j], amin = argmin.
// ---------------------------------------------------------------------------
__global__ __launch_bounds__(256) void colred_kernel(
    const float* __restrict__ cost, float* __restrict__ v0, int* __restrict__ amin)
{
    const int j = blockIdx.x * 256 + threadIdx.x;
    const int b = blockIdx.y;
    if (j >= Nq) return;
    const float* __restrict__ cb = cost + (size_t)b * Mq * Nq;
    float best = INFINITY;
    int bi = 0;
    #pragma unroll 4
    for (int i = 0; i < Mq; ++i) {
        const float c = cb[(size_t)i * Nq + j];
        if (c < best) { best = c; bi = i; }
    }
    v0[b * Nq + j] = best;
    amin[b * Nq + j] = bi;
}

// ---------------------------------------------------------------------------
// Value-only wave64 min: 6 x v_min_f32_dpp (single instr/step) + readlane.
// min over floats (no NaN, no -0 here) is associative => bit-exact gmin.
// ---------------------------------------------------------------------------
template<int CTRL>
__device__ __forceinline__ float dppminv_(float x) {
    const int moved = __builtin_amdgcn_update_dpp(
        0x7F800000, __float_as_int(x), CTRL, 0xF, 0xF, false);
    return fminf(x, __int_as_float(moved));
}
__device__ __forceinline__ float wave_min_f32_(float x) {
    x = dppminv_<0x111>(x);
    x = dppminv_<0x112>(x);
    x = dppminv_<0x114>(x);
    x = dppminv_<0x118>(x);
    x = dppminv_<0x142>(x);
    x = dppminv_<0x143>(x);
    return __int_as_float(__builtin_amdgcn_readlane(__float_as_int(x), 63));
}

// local fused (value,payload) merge — cmp + min + cndmask
__device__ __forceinline__ void pairmin_(float& va, unsigned& pa, float vb, unsigned pb) {
    const bool le = (va <= vb);
    va = fminf(va, vb);
    pa = le ? pa : pb;
}

__device__ __forceinline__ unsigned long long pack_bid_(float p, int row) {
    // p >= 0 -> float bits are order-preserving; row+1 in low word (0 = no bid)
    return ((unsigned long long)__float_as_uint(p) << 32) | (unsigned)(row + 1);
}

// ---------------------------------------------------------------------------
// Phase 1.75: eps-SCALING synchronous auction (R11/R12 proven) with the R13
// SLACK-GUARANTEED commit. Diagnosis: the final bid on a contested column
// makes the winner INDIFFERENT (rc1 == mu within ~2-3 ulp); the transfer
// re-derives rc1/mu through a different float path, so the keep-check was a
// coin flip for exactly the contested rows — they leaked into serial SSP no
// matter how long the auction ran. Fix:
//   - UNDERPAY the bid: pnew = p + max(g2-g1 - 1e-6, 0) + eps. Committed
//     polish edges then carry >= ~6e-7 slack, beating the <= ~4.3e-7
//     cross-arithmetic noise (c,v0 <= 1.2 => ulp <= 2.4e-7) => keep-check
//     passes deterministically. mu only rises after commit (prices rise,
//     float add monotone). eps-phase edges are discarded anyway.
//   - PARK tie rows in the polish: gap <= 1e-6 => zero increment => would
//     ping-pong; set match = -2 (excluded from worklist), resolved by exact
//     SSP (~30us each, expected 1-5/batch). Makes nf==0 early-exit real.
// Feasibility unchanged: prices only rise => v = v0 - p only falls =>
// c - v >= 0; robust transfer still re-verifies every edge.
// ---------------------------------------------------------------------------
__global__ __launch_bounds__(1024) void auction_kernel(
    const float* __restrict__ cost, const float* __restrict__ v0,
    const int* __restrict__ amin,
    float* __restrict__ v_out, int* __restrict__ owner_out)
{
    constexpr int n = Nq;  // 500
    __shared__ float p_lds[512];
    __shared__ int   owner_lds[512];   // col -> row
    __shared__ int   match_lds[512];   // row -> col; -1 free, -2 parked
    __shared__ unsigned long long bid_lds[512];
    __shared__ int   flist[512];       // free-row worklist (fresh each round)
    __shared__ int   jlist[512];       // columns bid this round (dups ok)
    __shared__ int   nfree_lds, njl_lds;

    const float eps_tab[NPHASE] = {4e-3f, 1e-3f, 2.5e-4f, 6e-5f, 1.5e-5f, 0.0f};
    const int   cap_tab[NPHASE] = {48, 32, 32, 32, 32, 256};

    const int tid = threadIdx.x;
    const int lane = tid & 63;
    const int wv = tid >> 6;           // 0..15
    const int b = blockIdx.x;
    const float* __restrict__ cb = cost + (size_t)b * n * n;

    const unsigned init_mask = (lane < 61) ? 0xFFu : 0x0Fu;
    const int off2 = (lane < 61) ? 256 + 4 * lane : 0;

    // v0 cached per lane (constant; effective v = v0 - p)
    float v0_r[8];
    {
        const float4 a0 = *(const float4*)(v0 + b * n + 4 * lane);
        const float4 a1 = *(const float4*)(v0 + b * n + off2);
        const float vv[8] = {a0.x, a0.y, a0.z, a0.w, a1.x, a1.y, a1.z, a1.w};
        #pragma unroll
        for (int k = 0; k < 8; ++k)
            v0_r[k] = ((init_mask >> k) & 1) ? vv[k] : 0.0f;
    }
    if (tid < 512) {
        p_lds[tid] = 0.0f; owner_lds[tid] = -1; match_lds[tid] = -1;
        bid_lds[tid] = 0ull;
    }
    __syncthreads();
    // greedy seed (parallel CAS): col j claims its col-argmin row if free.
    if (tid < n) {
        const int i0 = amin[b * n + tid];
        if (atomicCAS(&match_lds[i0], -1, tid) == -1) owner_lds[tid] = i0;
    }
    __syncthreads();

    for (int ph = 0; ph < NPHASE; ++ph) {
        const float eps = eps_tab[ph];
        const int cap = cap_tab[ph];
        const bool polish = (eps == 0.0f);
        if (ph > 0) {   // phase boundary: unmatch all, KEEP prices
            if (tid < 512) { owner_lds[tid] = -1; match_lds[tid] = -1; }
        }
        __syncthreads();

        for (int round = 0; round < cap; ++round) {
            // ---- compact free-row worklist (parked rows excluded) ----
            if (tid == 0) { nfree_lds = 0; njl_lds = 0; }
            __syncthreads();
            if (tid < n && match_lds[tid] == -1)
                flist[atomicAdd(&nfree_lds, 1)] = tid;
            __syncthreads();
            const int nf = nfree_lds;          // uniform after barrier
            if (nf == 0) break;                // phase complete

            // ---- bid phase: one wave per free row ----
            for (int idx = wv; idx < nf; idx += 16) {
                const int i = flist[idx];                 // uniform read
                const float* __restrict__ crow = cb + (size_t)i * n;
                const float4 c0 = *(const float4*)(crow + 4 * lane);
                const float4 c1 = *(const float4*)(crow + off2);
                const float4 p0 = *(const float4*)&p_lds[4 * lane];
                const float4 p1 = *(const float4*)&p_lds[off2];
                const float cc[8] = {c0.x, c0.y, c0.z, c0.w, c1.x, c1.y, c1.z, c1.w};
                const float pp[8] = {p0.x, p0.y, p0.z, p0.w, p1.x, p1.y, p1.z, p1.w};
                float d[8]; unsigned pj[8];
                #pragma unroll
                for (int k = 0; k < 8; ++k) {
                    const int j = (k < 4) ? 4 * lane + k : 256 + 4 * lane + (k - 4);
                    d[k] = ((init_mask >> k) & 1) ? cc[k] - v0_r[k] + pp[k] : INFINITY;
                    pj[k] = (unsigned)j;
                }
                float    a0 = d[0], a1 = d[1], a2 = d[2], a3 = d[3];
                float    a4 = d[4], a5 = d[5], a6 = d[6], a7 = d[7];
                unsigned b0 = pj[0], b1 = pj[1], b2 = pj[2], b3 = pj[3];
                unsigned b4 = pj[4], b5 = pj[5], b6 = pj[6], b7 = pj[7];
                pairmin_(a0, b0, a1, b1);  pairmin_(a2, b2, a3, b3);
                pairmin_(a4, b4, a5, b5);  pairmin_(a6, b6, a7, b7);
                pairmin_(a0, b0, a2, b2);  pairmin_(a4, b4, a6, b6);
                pairmin_(a0, b0, a4, b4);
                const float lmin = a0;
                const unsigned lpay = b0;

                const float g1 = wave_min_f32_(lmin);
                const unsigned long long cm = __ballot(lmin == g1);
                const int wl = (int)__builtin_ctzll(cm);
                const int j1 = __builtin_amdgcn_readlane((int)lpay, wl);

                // second-best: poison j1 on its owner lane, value-only re-reduce
                const int ow = (j1 >> 2) & 63, kw = ((j1 >> 8) << 2) | (j1 & 3);
                float lmin2 = INFINITY;
                #pragma unroll
                for (int k = 0; k < 8; ++k) {
                    const float dv = (k == kw && lane == ow) ? INFINITY : d[k];
                    lmin2 = fminf(lmin2, dv);
                }
                const float g2 = wave_min_f32_(lmin2);

                if (lane == 0) {
                    const float inc = g2 - g1;       // >= 0
                    if (polish && inc <= AUC_UNDERPAY) {
                        match_lds[i] = -2;           // park: tie row -> exact SSP
                    } else {
                        // slack-guaranteed commit: underpay by AUC_UNDERPAY
                        const float pnew = p_lds[j1]
                            + fmaxf(inc - AUC_UNDERPAY, 0.0f) + eps;
                        atomicMax(&bid_lds[j1], pack_bid_(pnew, i));
                        jlist[atomicAdd(&njl_lds, 1)] = j1;
                    }
                }
            }
            __syncthreads();

            // ---- assignment: only the columns that received bids ----
            const int nj = njl_lds;
            for (int t = tid; t < nj; t += 1024) {
                const int j = jlist[t];
                const unsigned long long bd = atomicExch(&bid_lds[j], 0ull);
                if (bd != 0ull) {      // dups see 0 after first exchange
                    const int ri = (int)(bd & 0xFFFFFFFFull) - 1;
                    const float pn = __uint_as_float((unsigned)(bd >> 32));
                    const int prev = owner_lds[j];
                    if (prev >= 0) match_lds[prev] = -1;   // evictee didn't bid
                    owner_lds[j] = ri;
                    match_lds[ri] = j;
                    p_lds[j] = pn;
                }
            }
            __syncthreads();
        }
    }

    if (tid < n) {
        v_out[b * n + tid] = v0[b * n + tid] - p_lds[tid];
        owner_out[b * n + tid] = owner_lds[tid];
    }
}

// ---------------------------------------------------------------------------
// Phase 2: exact successive-shortest-path LAP — R4's proven SSP verbatim,
// init from the auction state. Robust transfer (R7, proven): a matched edge
// is kept (tightened: v[j1] = c - mu <= v_old, u = mu) only if its reduced
// cost rc1 <= mu; otherwise the row is freed into SSP and v is untouched.
// Init hardened with atomicCAS row-claiming (R10, proven).
// ---------------------------------------------------------------------------
__global__ __launch_bounds__(64) void lsa_kernel(
    const float* __restrict__ cost, const float* __restrict__ v_in,
    const int* __restrict__ owner_in, int* __restrict__ mapping)
{
    constexpr int n = Nq;  // 500
    __shared__ float u_lds[512];
    __shared__ float shortest_lds[512];
    __shared__ int   path_lds[512];
    __shared__ int   row4col_lds[512];
    __shared__ int   col4row_lds[512];

    const int lane = threadIdx.x;
    const int b = blockIdx.x;
    const float* __restrict__ cb = cost + (size_t)b * n * n;

    // k<4 -> j = 4*lane+k ; k>=4 -> j = 256+4*lane+(k-4)
    const unsigned init_mask = (lane < 61) ? 0xFFu : 0x0Fu;
    const int off2 = (lane < 61) ? 256 + 4 * lane : 0;   // clamped 2nd-quad offset

    float v_r[8], vwork_r[8], short_r[8], shortfin_r[8], t_r[8];
    int path_r[8];
    unsigned pay_r[8];   // (j<<10) | (row4col[j]+1)

    // --- duals + matching from the auction pre-pass ---
    {
        const float4 a0 = *(const float4*)(v_in + b * n + 4 * lane);
        const float4 a1 = *(const float4*)(v_in + b * n + off2);
        const float vv[8] = {a0.x, a0.y, a0.z, a0.w, a1.x, a1.y, a1.z, a1.w};
        #pragma unroll
        for (int k = 0; k < 8; ++k)
            v_r[k] = ((init_mask >> k) & 1) ? vv[k] : 0.0f;
    }
    for (int t = lane; t < 512; t += 64) {
        u_lds[t] = 0.0f; row4col_lds[t] = -1; col4row_lds[t] = -1;
    }
    __syncthreads();
    for (int t = lane; t < n; t += 64) {
        const int r = owner_in[b * n + t];
        if (r >= 0 && atomicCAS(&col4row_lds[r], -1, t) == -1)
            row4col_lds[t] = r;    // mutual consistency guaranteed
    }
    __syncthreads();

    // --- JV reduction transfer (robust), software-pipelined ---
    {
        int j1c = col4row_lds[0];
        float4 ta0 = *(const float4*)(cb + 4 * lane);
        float4 ta1 = *(const float4*)(cb + off2);
        for (int i2 = 0; i2 < n; ++i2) {
            const float4 c0 = ta0, c1 = ta1;
            const int j1 = j1c;
            const int inx = (i2 + 1 < n) ? i2 + 1 : i2;
            const float* __restrict__ crn = cb + (size_t)inx * n;
            ta0 = *(const float4*)(crn + 4 * lane);
            ta1 = *(const float4*)(crn + off2);
            j1c = col4row_lds[inx];
            if (j1 < 0) continue;                  // free row: no transfer
            const float cc[8] = {c0.x, c0.y, c0.z, c0.w, c1.x, c1.y, c1.z, c1.w};
            const int owner = (j1 >> 2) & 63;      // wave-uniform
            const int kwin  = ((j1 >> 8) << 2) | (j1 & 3);
            float d[8];
            float rcj = INFINITY;                  // reduced cost at j1 (owner lane)
            #pragma unroll
            for (int k = 0; k < 8; ++k) {
                const bool mine = (k == kwin && lane == owner);
                const bool use = ((init_mask >> k) & 1) && !mine;
                d[k] = use ? cc[k] - v_r[k] : INFINITY;
                if (mine) rcj = cc[k] - v_r[k];
            }
            const float mu = wave_min_f32_(
                fminf(fminf(fminf(d[0], d[1]), fminf(d[2], d[3])),
                      fminf(fminf(d[4], d[5]), fminf(d[6], d[7]))));
            const float rc1g = __int_as_float(
                __builtin_amdgcn_readlane(__float_as_int(rcj), owner));
            const bool keep = (rc1g <= mu);        // j1 is row argmin
            #pragma unroll
            for (int k = 0; k < 8; ++k)
                if (keep && k == kwin && lane == owner) v_r[k] = cc[k] - mu;
            if (lane == 0) {
                if (keep) u_lds[i2] = mu;
                else { row4col_lds[j1] = -1; col4row_lds[i2] = -1; }  // free row
            }
        }
    }
    __syncthreads();

    {
        const int4 r0 = *(const int4*)&row4col_lds[4 * lane];
        const int4 r1 = *(const int4*)&row4col_lds[off2];
        const int rr[8] = {r0.x, r0.y, r0.z, r0.w, r1.x, r1.y, r1.z, r1.w};
        #pragma unroll
        for (int k = 0; k < 8; ++k) {
            const int j = (k < 4) ? 4 * lane + k : 256 + 4 * lane + (k - 4);
            const bool valid = (init_mask >> k) & 1;
            pay_r[k] = valid ? (((unsigned)j << 10) | (unsigned)(rr[k] + 1))
                             : 0xFFFFFFFFu;
            vwork_r[k] = valid ? v_r[k] : -INFINITY;
            short_r[k] = INFINITY;
            shortfin_r[k] = INFINITY;
            path_r[k] = -1;
        }
    }
    for (int t = lane; t < n; t += 64)
        path_lds[t] = -1;
    unsigned sr_mask = 0;
    __syncthreads();

    // --- successive shortest paths over free rows (R4 verbatim) ---
    for (int cur_row = 0; cur_row < n; ++cur_row) {
        if (col4row_lds[cur_row] >= 0) continue;   // wave-uniform

        int sink_j = -1;
        int i = cur_row;
        float min_val = 0.0f;
        const float* __restrict__ crow = cb + (size_t)i * n;
        float4 cv0 = *(const float4*)(crow + 4 * lane);     // prologue loads
        float4 cv1 = *(const float4*)(crow + off2);
        float a = -u_lds[cur_row];                           // a = min_val - u[i]

        for (int pops = 0; pops < n; ++pops) {
            if ((i & 63) == lane) sr_mask |= 1u << (i >> 6);

            // t_r fills the load shadow (a known since last reduction)
            #pragma unroll
            for (int k = 0; k < 8; ++k) t_r[k] = a - vwork_r[k];

            // relax quad0 (cv0) then quad1 (cv1): quad0 can start at vmcnt(1)
            {
                const float c4[4] = {cv0.x, cv0.y, cv0.z, cv0.w};
                #pragma unroll
                for (int k = 0; k < 4; ++k) {
                    const float r = c4[k] + t_r[k];
                    if (r < short_r[k]) { short_r[k] = r; path_r[k] = i; }
                }
            }
            {
                const float c4[4] = {cv1.x, cv1.y, cv1.z, cv1.w};
                #pragma unroll
                for (int k = 0; k < 4; ++k) {
                    const float r = c4[k] + t_r[4 + k];
                    if (r < short_r[4 + k]) { short_r[4 + k] = r; path_r[4 + k] = i; }
                }
            }

            // fused local argmin tree (prefers lower k = lower j per lane)
            float    m0 = short_r[0], m1 = short_r[1], m2 = short_r[2], m3 = short_r[3];
            float    m4 = short_r[4], m5 = short_r[5], m6 = short_r[6], m7 = short_r[7];
            unsigned q0 = pay_r[0], q1 = pay_r[1], q2 = pay_r[2], q3 = pay_r[3];
            unsigned q4 = pay_r[4], q5 = pay_r[5], q6 = pay_r[6], q7 = pay_r[7];
            pairmin_(m0, q0, m1, q1);  pairmin_(m2, q2, m3, q3);
            pairmin_(m4, q4, m5, q5);  pairmin_(m6, q6, m7, q7);
            pairmin_(m0, q0, m2, q2);  pairmin_(m4, q4, m6, q6);
            pairmin_(m0, q0, m4, q4);
            const float lmin = m0;                 // per-lane local min
            const unsigned lpay = q0;              // its payload

            // value-only wave min (bit-exact gmin), then ballot-select owner
            const float gmin = wave_min_f32_(lmin);
            const unsigned long long cand = __ballot(lmin == gmin);
            const int wl = (int)__builtin_ctzll(cand);
            const unsigned win = (unsigned)__builtin_amdgcn_readlane((int)lpay, wl);

            min_val = gmin;
            const unsigned jst = win >> 10;
            const unsigned rc1 = win & 0x3FFu;

            // issue next-row loads EARLY (clamped on sink); bookkeeping hides
            const int i_next = (int)rc1 - 1;                 // -1 if sink
            const int i_safe = (i_next < 0) ? 0 : i_next;
            crow = cb + (size_t)i_safe * n;
            cv0 = *(const float4*)(crow + 4 * lane);
            cv1 = *(const float4*)(crow + off2);
            a = gmin - u_lds[i_safe];             // LDS read in load shadow

            // pop bookkeeping: poison winner col on its owner lane
            const int owner = (int)((jst >> 2) & 63u);
            const int kwin  = (int)(((jst >> 8) << 2) | (jst & 3u));
            #pragma unroll
            for (int k = 0; k < 8; ++k) {
                if (k == kwin && lane == owner) {
                    shortfin_r[k] = short_r[k];
                    short_r[k] = INFINITY;
                    vwork_r[k] = -INFINITY;
                }
            }

            if (rc1 == 0u) { sink_j = (int)jst; break; }
            i = i_next;
        }

        if (sink_j >= 0) {
            // publish final labels/path (vectorized; lanes 61-63's 2nd quad
            // lands in the unread 500..511 pad -> literal offset, NOT off2)
            *(float4*)&shortest_lds[4 * lane] =
                make_float4(shortfin_r[0], shortfin_r[1], shortfin_r[2], shortfin_r[3]);
            *(int4*)&path_lds[4 * lane] =
                make_int4(path_r[0], path_r[1], path_r[2], path_r[3]);
            *(float4*)&shortest_lds[256 + 4 * lane] =
                make_float4(shortfin_r[4], shortfin_r[5], shortfin_r[6], shortfin_r[7]);
            *(int4*)&path_lds[256 + 4 * lane] =
                make_int4(path_r[4], path_r[5], path_r[6], path_r[7]);
            __syncthreads();

            // u-update for SR rows (col4row read BEFORE augmentation);
            // v-update for scanned cols (marker: vwork == -INF), register-local
            #pragma unroll
            for (int k = 0; k < 8; ++k) {
                const int t = lane + (k << 6);
                if (t < n && (sr_mask & (1u << k))) {
                    if (t == cur_row) u_lds[t] += min_val;
                    else              u_lds[t] += min_val - shortest_lds[col4row_lds[t]];
                }
            }
            #pragma unroll
            for (int k = 0; k < 8; ++k) {
                if (((init_mask >> k) & 1) && vwork_r[k] == -INFINITY)
                    v_r[k] -= min_val - shortfin_r[k];
            }
            __syncthreads();

            if (lane == 0) {   // augment alternating path
                int j = sink_j;
                for (;;) {
                    const int ii = path_lds[j];
                    row4col_lds[j] = ii;
                    const int tmp = col4row_lds[ii];
                    col4row_lds[ii] = j;
                    j = tmp;
                    if (ii == cur_row) break;
                }
            }
            __syncthreads();
        }

        // refresh payloads (b128 LDS reads) and reset per-row register state
        {
            const int4 r0 = *(const int4*)&row4col_lds[4 * lane];
            const int4 r1 = *(const int4*)&row4col_lds[off2];
            const int rr[8] = {r0.x, r0.y, r0.z, r0.w, r1.x, r1.y, r1.z, r1.w};
            #pragma unroll
            for (int k = 0; k < 8; ++k) {
                const int j = (k < 4) ? 4 * lane + k : 256 + 4 * lane + (k - 4);
                const bool valid = (init_mask >> k) & 1;
                pay_r[k] = valid ? (((unsigned)j << 10) | (unsigned)(rr[k] + 1))
                                 : 0xFFFFFFFFu;
                vwork_r[k] = valid ? v_r[k] : -INFINITY;
                short_r[k] = INFINITY;
                shortfin_r[k] = INFINITY;
                path_r[k] = -1;
            }
        }
        sr_mask = 0;
        __syncthreads();
    }

    for (int t = lane; t < n; t += 64)
        mapping[b * n + t] = col4row_lds[t];
}

// ---------------------------------------------------------------------------
// Phase 3: extrapolation (square problem => every row assigned; -1 guarded).
// ---------------------------------------------------------------------------
__global__ __launch_bounds__(256) void extrap_boxes_kernel(
    const float* __restrict__ p1_boxes, const float* __restrict__ p2_boxes,
    const float* __restrict__ toffs, const int* __restrict__ mapping,
    float* __restrict__ out_boxes)
{
    const int idx = blockIdx.x * blockDim.x + threadIdx.x;  // b*Mq + i
    if (idx >= Bq * Mq) return;
    const int b = idx / Mq;
    const float t0 = toffs[b * 3 + 0], t1 = toffs[b * 3 + 1], t2 = toffs[b * 3 + 2];
    const float factor = (t2 - t1) / (t1 - t0);
    const int m = mapping[idx];
    const float4 p2 = ((const float4*)p2_boxes)[idx];
    const float4 p1 = (m >= 0) ? ((const float4*)p1_boxes)[b * Nq + m] : p2;
    float4 o;
    o.x = p2.x + (p2.x - p1.x) * factor;
    o.y = p2.y + (p2.y - p1.y) * factor;
    o.z = fmaxf(p2.z + (p2.z - p1.z) * factor, 0.0f);
    o.w = fmaxf(p2.w + (p2.w - p1.w) * factor, 0.0f);
    ((float4*)out_boxes)[idx] = o;
}

__global__ __launch_bounds__(256) void extrap_logits_kernel(
    const float* __restrict__ p1_logits, const float* __restrict__ p2_logits,
    const int* __restrict__ mapping, float* __restrict__ out_logits)
{
    const int idx = blockIdx.x * blockDim.x + threadIdx.x;  // (b*Mq + i)*Cq + c
    if (idx >= Bq * Mq * Cq) return;
    const int c = idx % Cq;
    const int bi = idx / Cq;
    const int b = bi / Mq;
    const int m = mapping[bi];
    const float corr = (m >= 0) ? p1_logits[((size_t)b * Nq + m) * Cq + c] : 0.0f;
    out_logits[idx] = 0.5f * (p2_logits[idx] + corr);
}

// ---------------------------------------------------------------------------
extern "C" void kernel_launch(void* const* d_in, const int* in_sizes, int n_in,
                              void* d_out, int out_size, void* d_ws, size_t ws_size,
                              hipStream_t stream) {
    const float* p1_boxes  = (const float*)d_in[0];  // (B,N,4)
    const float* p1_logits = (const float*)d_in[1];  // (B,N,C)
    const float* p2_boxes  = (const float*)d_in[2];  // (B,M,4)
    const float* p2_logits = (const float*)d_in[3];  // (B,M,C)
    const float* toffs     = (const float*)d_in[4];  // (B,3)
    float* out = (float*)d_out;                      // boxes3 ++ logits3

    char* ws = (char*)d_ws;
    float* cost    = (float*)ws;                                   // 4 MB
    int*   mapping = (int*)  (ws + 4000000);                       // 8 KB
    float* v0      = (float*)(ws + 4008000);                       // 8 KB
    int*   amin    = (int*)  (ws + 4016000);                       // 8 KB
    float* v_auc   = (float*)(ws + 4024000);                       // 8 KB
    int*   owner   = (int*)  (ws + 4032000);                       // 8 KB

    dim3 cgrid((Nq + 15) / 16, (Mq + 15) / 16, Bq);
    cost_kernel<<<cgrid, 256, 0, stream>>>(p1_boxes, p1_logits, p2_boxes, p2_logits, cost);

    colred_kernel<<<dim3(2, Bq), 256, 0, stream>>>(cost, v0, amin);

    auction_kernel<<<Bq, 1024, 0, stream>>>(cost, v0, amin, v_auc, owner);

    lsa_kernel<<<Bq, 64, 0, stream>>>(cost, v_auc, owner, mapping);

    extrap_boxes_kernel<<<(Bq * Mq + 255) / 256, 256, 0, stream>>>(
        p1_boxes, p2_boxes, toffs, mapping, out);
    extrap_logits_kernel<<<(Bq * Mq * Cq + 255) / 256, 256, 0, stream>>>(
        p1_logits, p2_logits, mapping, out + Bq * Mq * 4);
}

// Round 14
// 2004.810 us; speedup vs baseline: 1.2209x; 1.2209x over previous
//
#include <hip/hip_runtime.h>
#include <math.h>

#define Bq 4
#define Mq 500
#define Nq 500
#define Cq 91
#define NPHASE 5

// ---------------------------------------------------------------------------
// Phase 1: cost[b,i,j] = 0.5*||center2_i - center1_j||_2
//                      + 0.5*max_c |sigmoid(l2[i,c]) - sigmoid(l1[j,c])|
// ---------------------------------------------------------------------------
__device__ __forceinline__ float sigmoidf_(float x) {
    return 1.0f / (1.0f + expf(-x));
}

__global__ __launch_bounds__(256) void cost_kernel(
    const float* __restrict__ p1_boxes, const float* __restrict__ p1_logits,
    const float* __restrict__ p2_boxes, const float* __restrict__ p2_logits,
    float* __restrict__ cost)
{
    __shared__ float s2t[16][Cq + 1];   // stride 92 -> 2-way bank alias (free)
    __shared__ float s1t[16][Cq + 1];
    __shared__ float b2x[16], b2y[16], b1x[16], b1y[16];
    const int b  = blockIdx.z;
    const int i0 = blockIdx.y * 16;
    const int j0 = blockIdx.x * 16;
    const int tid = threadIdx.x;

    for (int t = tid; t < 16 * Cq; t += 256) {
        const int r = t / Cq, c = t - r * Cq;
        const int i = min(i0 + r, Mq - 1);
        const int j = min(j0 + r, Nq - 1);
        s2t[r][c] = sigmoidf_(p2_logits[((size_t)b * Mq + i) * Cq + c]);
        s1t[r][c] = sigmoidf_(p1_logits[((size_t)b * Nq + j) * Cq + c]);
    }
    if (tid < 16) {
        const int i = min(i0 + tid, Mq - 1);
        const int j = min(j0 + tid, Nq - 1);
        b2x[tid] = p2_boxes[((size_t)b * Mq + i) * 4 + 0];
        b2y[tid] = p2_boxes[((size_t)b * Mq + i) * 4 + 1];
        b1x[tid] = p1_boxes[((size_t)b * Nq + j) * 4 + 0];
        b1y[tid] = p1_boxes[((size_t)b * Nq + j) * 4 + 1];
    }
    __syncthreads();

    const int ty = tid >> 4, tx = tid & 15;
    const int i = i0 + ty, j = j0 + tx;
    if (i < Mq && j < Nq) {
        float mx = 0.0f;
        #pragma unroll 7
        for (int c = 0; c < Cq; ++c)
            mx = fmaxf(mx, fabsf(s2t[ty][c] - s1t[tx][c]));
        const float dx = b2x[ty] - b1x[tx];
        const float dy = b2y[ty] - b1y[tx];
        const float cd = sqrtf(dx * dx + dy * dy);
        cost[((size_t)b * Mq + i) * Nq + j] = 0.5f * cd + 0.5f * mx;
    }
}

// ---------------------------------------------------------------------------
// Phase 1.5: column reduction. v0[b][j] = min_i cost[b][i][j], amin = argmin.
// ---------------------------------------------------------------------------
__global__ __launch_bounds__(256) void colred_kernel(
    const float* __restrict__ cost, float* __restrict__ v0, int* __restrict__ amin)
{
    const int j = blockIdx.x * 256 + threadIdx.x;
    const int b = blockIdx.y;
    if (j >= Nq) return;
    const float* __restrict__ cb = cost + (size_t)b * Mq * Nq;
    float best = INFINITY;
    int bi = 0;
    #pragma unroll 4
    for (int i = 0; i < Mq; ++i) {
        const float c = cb[(size_t)i * Nq + j];
        if (c < best) { best = c; bi = i; }
    }
    v0[b * Nq + j] = best;
    amin[b * Nq + j] = bi;
}

// ---------------------------------------------------------------------------
// Value-only wave64 min: 6 x v_min_f32_dpp (single instr/step) + readlane.
// min over floats (no NaN, no -0 here) is associative => bit-exact gmin.
// ---------------------------------------------------------------------------
template<int CTRL>
__device__ __forceinline__ float dppminv_(float x) {
    const int moved = __builtin_amdgcn_update_dpp(
        0x7F800000, __float_as_int(x), CTRL, 0xF, 0xF, false);
    return fminf(x, __int_as_float(moved));
}
__device__ __forceinline__ float wave_min_f32_(float x) {
    x = dppminv_<0x111>(x);
    x = dppminv_<0x112>(x);
    x = dppminv_<0x114>(x);
    x = dppminv_<0x118>(x);
    x = dppminv_<0x142>(x);
    x = dppminv_<0x143>(x);
    return __int_as_float(__builtin_amdgcn_readlane(__float_as_int(x), 63));
}

// local fused (value,payload) merge — cmp + min + cndmask
__device__ __forceinline__ void pairmin_(float& va, unsigned& pa, float vb, unsigned pb) {
    const bool le = (va <= vb);
    va = fminf(va, vb);
    pa = le ? pa : pb;
}

__device__ __forceinline__ unsigned long long pack_bid_(float p, int row) {
    // p >= 0 -> float bits are order-preserving; row+1 in low word (0 = no bid)
    return ((unsigned long long)__float_as_uint(p) << 32) | (unsigned)(row + 1);
}

// ---------------------------------------------------------------------------
// Phase 1.75: eps-SCALING synchronous auction — R11 config verbatim (best
// measured; R12's longer schedule and R13's underpay/park both regressed:
// marginal polish rounds resolve hard rows no cheaper than SSP does).
// Phases bid (g2-g1)+eps, eps {4e-3,8e-4,1.6e-4,3.2e-5,0}; phase boundary
// unmatches all rows (prices kept); final eps=0 polish from near-optimal
// prices. Leftover hard rows go to the (now multi-source) exact SSP.
// Feasibility: prices only rise => v = v0 - p only falls => c - v >= 0.
// ---------------------------------------------------------------------------
__global__ __launch_bounds__(1024) void auction_kernel(
    const float* __restrict__ cost, const float* __restrict__ v0,
    const int* __restrict__ amin,
    float* __restrict__ v_out, int* __restrict__ owner_out)
{
    constexpr int n = Nq;  // 500
    __shared__ float p_lds[512];
    __shared__ int   owner_lds[512];   // col -> row
    __shared__ int   match_lds[512];   // row -> col
    __shared__ unsigned long long bid_lds[512];
    __shared__ int   flist[512];       // compacted free-row worklist
    __shared__ int   jlist[512];       // columns bid this round (dups ok)
    __shared__ int   nfree_lds, njl_lds;

    const float eps_tab[NPHASE] = {4e-3f, 8e-4f, 1.6e-4f, 3.2e-5f, 0.0f};
    const int   cap_tab[NPHASE] = {48, 32, 32, 32, 64};

    const int tid = threadIdx.x;
    const int lane = tid & 63;
    const int wv = tid >> 6;           // 0..15
    const int b = blockIdx.x;
    const float* __restrict__ cb = cost + (size_t)b * n * n;

    const unsigned init_mask = (lane < 61) ? 0xFFu : 0x0Fu;
    const int off2 = (lane < 61) ? 256 + 4 * lane : 0;

    // v0 cached per lane (constant; effective v = v0 - p)
    float v0_r[8];
    {
        const float4 a0 = *(const float4*)(v0 + b * n + 4 * lane);
        const float4 a1 = *(const float4*)(v0 + b * n + off2);
        const float vv[8] = {a0.x, a0.y, a0.z, a0.w, a1.x, a1.y, a1.z, a1.w};
        #pragma unroll
        for (int k = 0; k < 8; ++k)
            v0_r[k] = ((init_mask >> k) & 1) ? vv[k] : 0.0f;
    }
    if (tid < 512) {
        p_lds[tid] = 0.0f; owner_lds[tid] = -1; match_lds[tid] = -1;
        bid_lds[tid] = 0ull;
    }
    __syncthreads();
    // greedy seed (parallel CAS): col j claims its col-argmin row if free.
    if (tid < n) {
        const int i0 = amin[b * n + tid];
        if (atomicCAS(&match_lds[i0], -1, tid) == -1) owner_lds[tid] = i0;
    }
    __syncthreads();

    for (int ph = 0; ph < NPHASE; ++ph) {
        const float eps = eps_tab[ph];
        const int cap = cap_tab[ph];
        if (ph > 0) {   // phase boundary: unmatch all, KEEP prices
            if (tid < 512) { owner_lds[tid] = -1; match_lds[tid] = -1; }
        }
        __syncthreads();

        for (int round = 0; round < cap; ++round) {
            // ---- compact free-row worklist (every round: fresh) ----
            if (tid == 0) { nfree_lds = 0; njl_lds = 0; }
            __syncthreads();
            if (tid < n && match_lds[tid] < 0)
                flist[atomicAdd(&nfree_lds, 1)] = tid;
            __syncthreads();
            const int nf = nfree_lds;          // uniform after barrier
            if (nf == 0) break;                // phase complete

            // ---- bid phase: one wave per free row ----
            for (int idx = wv; idx < nf; idx += 16) {
                const int i = flist[idx];                 // uniform read
                const float* __restrict__ crow = cb + (size_t)i * n;
                const float4 c0 = *(const float4*)(crow + 4 * lane);
                const float4 c1 = *(const float4*)(crow + off2);
                const float4 p0 = *(const float4*)&p_lds[4 * lane];
                const float4 p1 = *(const float4*)&p_lds[off2];
                const float cc[8] = {c0.x, c0.y, c0.z, c0.w, c1.x, c1.y, c1.z, c1.w};
                const float pp[8] = {p0.x, p0.y, p0.z, p0.w, p1.x, p1.y, p1.z, p1.w};
                float d[8]; unsigned pj[8];
                #pragma unroll
                for (int k = 0; k < 8; ++k) {
                    const int j = (k < 4) ? 4 * lane + k : 256 + 4 * lane + (k - 4);
                    d[k] = ((init_mask >> k) & 1) ? cc[k] - v0_r[k] + pp[k] : INFINITY;
                    pj[k] = (unsigned)j;
                }
                float    a0 = d[0], a1 = d[1], a2 = d[2], a3 = d[3];
                float    a4 = d[4], a5 = d[5], a6 = d[6], a7 = d[7];
                unsigned b0 = pj[0], b1 = pj[1], b2 = pj[2], b3 = pj[3];
                unsigned b4 = pj[4], b5 = pj[5], b6 = pj[6], b7 = pj[7];
                pairmin_(a0, b0, a1, b1);  pairmin_(a2, b2, a3, b3);
                pairmin_(a4, b4, a5, b5);  pairmin_(a6, b6, a7, b7);
                pairmin_(a0, b0, a2, b2);  pairmin_(a4, b4, a6, b6);
                pairmin_(a0, b0, a4, b4);
                const float lmin = a0;
                const unsigned lpay = b0;

                const float g1 = wave_min_f32_(lmin);
                const unsigned long long cm = __ballot(lmin == g1);
                const int wl = (int)__builtin_ctzll(cm);
                const int j1 = __builtin_amdgcn_readlane((int)lpay, wl);

                // second-best: poison j1 on its owner lane, value-only re-reduce
                const int ow = (j1 >> 2) & 63, kw = ((j1 >> 8) << 2) | (j1 & 3);
                float lmin2 = INFINITY;
                #pragma unroll
                for (int k = 0; k < 8; ++k) {
                    const float dv = (k == kw && lane == ow) ? INFINITY : d[k];
                    lmin2 = fminf(lmin2, dv);
                }
                const float g2 = wave_min_f32_(lmin2);

                if (lane == 0) {
                    const float pnew = p_lds[j1] + (g2 - g1) + eps;
                    atomicMax(&bid_lds[j1], pack_bid_(pnew, i));
                    jlist[atomicAdd(&njl_lds, 1)] = j1;
                }
            }
            __syncthreads();

            // ---- assignment: only the columns that received bids ----
            const int nj = njl_lds;
            for (int t = tid; t < nj; t += 1024) {
                const int j = jlist[t];
                const unsigned long long bd = atomicExch(&bid_lds[j], 0ull);
                if (bd != 0ull) {      // dups see 0 after first exchange
                    const int ri = (int)(bd & 0xFFFFFFFFull) - 1;
                    const float pn = __uint_as_float((unsigned)(bd >> 32));
                    const int prev = owner_lds[j];
                    if (prev >= 0) match_lds[prev] = -1;   // evictee didn't bid
                    owner_lds[j] = ri;
                    match_lds[ri] = j;
                    p_lds[j] = pn;
                }
            }
            __syncthreads();
        }
    }

    if (tid < n) {
        v_out[b * n + tid] = v0[b * n + tid] - p_lds[tid];
        owner_out[b * n + tid] = owner_lds[tid];
    }
}

// ---------------------------------------------------------------------------
// Phase 2: exact LAP finisher. R14: MULTI-SOURCE successive shortest paths
// (min-cost-flow SSP with a super-source over ALL free rows). Each augment:
//   - seed short[j] = min over free rows i of c[i][j] - u[i] - v[j]
//     (origin tracked in path), software-pipelined row scans;
//   - the proven pop loop (unchanged) finds the GLOBALLY shortest
//     augmenting path (first free column popped);
//   - dual updates: scanned cols v -= minval - shortest (poison marker,
//     unchanged); scanned matched rows u += minval - shortest[col4row]
//     (sr_mask, unchanged); ALL free rows (dist-0 sources) u += minval
//     (replaces the cur_row special case). Textbook super-source SSP:
//     feasibility + tightness preserved; unique optimum => exact.
// Pops per augment collapse (nearest of F sinks from F sources) — this is
// the mechanism that resolves the ~35 hard rows/batch at far below the
// ~40us/row serial single-source cost.
// Robust transfer (R7) + hardened init (R10) unchanged.
// ---------------------------------------------------------------------------
__global__ __launch_bounds__(64) void lsa_kernel(
    const float* __restrict__ cost, const float* __restrict__ v_in,
    const int* __restrict__ owner_in, int* __restrict__ mapping)
{
    constexpr int n = Nq;  // 500
    __shared__ float u_lds[512];
    __shared__ float shortest_lds[512];
    __shared__ int   path_lds[512];
    __shared__ int   row4col_lds[512];
    __shared__ int   col4row_lds[512];
    __shared__ int   fr_lds[512];      // free-row list
    __shared__ int   nfr_lds;

    const int lane = threadIdx.x;
    const int b = blockIdx.x;
    const float* __restrict__ cb = cost + (size_t)b * n * n;

    // k<4 -> j = 4*lane+k ; k>=4 -> j = 256+4*lane+(k-4)
    const unsigned init_mask = (lane < 61) ? 0xFFu : 0x0Fu;
    const int off2 = (lane < 61) ? 256 + 4 * lane : 0;   // clamped 2nd-quad offset

    float v_r[8], vwork_r[8], short_r[8], shortfin_r[8], t_r[8];
    int path_r[8];
    unsigned pay_r[8];   // (j<<10) | (row4col[j]+1)

    // --- duals + matching from the auction pre-pass ---
    {
        const float4 a0 = *(const float4*)(v_in + b * n + 4 * lane);
        const float4 a1 = *(const float4*)(v_in + b * n + off2);
        const float vv[8] = {a0.x, a0.y, a0.z, a0.w, a1.x, a1.y, a1.z, a1.w};
        #pragma unroll
        for (int k = 0; k < 8; ++k)
            v_r[k] = ((init_mask >> k) & 1) ? vv[k] : 0.0f;
    }
    for (int t = lane; t < 512; t += 64) {
        u_lds[t] = 0.0f; row4col_lds[t] = -1; col4row_lds[t] = -1;
    }
    __syncthreads();
    for (int t = lane; t < n; t += 64) {
        const int r = owner_in[b * n + t];
        if (r >= 0 && atomicCAS(&col4row_lds[r], -1, t) == -1)
            row4col_lds[t] = r;    // mutual consistency guaranteed
    }
    __syncthreads();

    // --- JV reduction transfer (robust), software-pipelined ---
    {
        int j1c = col4row_lds[0];
        float4 ta0 = *(const float4*)(cb + 4 * lane);
        float4 ta1 = *(const float4*)(cb + off2);
        for (int i2 = 0; i2 < n; ++i2) {
            const float4 c0 = ta0, c1 = ta1;
            const int j1 = j1c;
            const int inx = (i2 + 1 < n) ? i2 + 1 : i2;
            const float* __restrict__ crn = cb + (size_t)inx * n;
            ta0 = *(const float4*)(crn + 4 * lane);
            ta1 = *(const float4*)(crn + off2);
            j1c = col4row_lds[inx];
            if (j1 < 0) continue;                  // free row: no transfer
            const float cc[8] = {c0.x, c0.y, c0.z, c0.w, c1.x, c1.y, c1.z, c1.w};
            const int owner = (j1 >> 2) & 63;      // wave-uniform
            const int kwin  = ((j1 >> 8) << 2) | (j1 & 3);
            float d[8];
            float rcj = INFINITY;                  // reduced cost at j1 (owner lane)
            #pragma unroll
            for (int k = 0; k < 8; ++k) {
                const bool mine = (k == kwin && lane == owner);
                const bool use = ((init_mask >> k) & 1) && !mine;
                d[k] = use ? cc[k] - v_r[k] : INFINITY;
                if (mine) rcj = cc[k] - v_r[k];
            }
            const float mu = wave_min_f32_(
                fminf(fminf(fminf(d[0], d[1]), fminf(d[2], d[3])),
                      fminf(fminf(d[4], d[5]), fminf(d[6], d[7]))));
            const float rc1g = __int_as_float(
                __builtin_amdgcn_readlane(__float_as_int(rcj), owner));
            const bool keep = (rc1g <= mu);        // j1 is row argmin
            #pragma unroll
            for (int k = 0; k < 8; ++k)
                if (keep && k == kwin && lane == owner) v_r[k] = cc[k] - mu;
            if (lane == 0) {
                if (keep) u_lds[i2] = mu;
                else { row4col_lds[j1] = -1; col4row_lds[i2] = -1; }  // free row
            }
        }
    }
    __syncthreads();

    // --- build free-row list ---
    if (lane == 0) nfr_lds = 0;
    __syncthreads();
    for (int t = lane; t < n; t += 64)
        if (col4row_lds[t] < 0) fr_lds[atomicAdd(&nfr_lds, 1)] = t;
    __syncthreads();

    // --- multi-source successive shortest paths ---
    for (int aug = 0; aug < n; ++aug) {
        const int nfr = nfr_lds;       // uniform after barrier
        if (nfr == 0) break;

        // per-augment state reset (payloads from current matching)
        {
            const int4 r0 = *(const int4*)&row4col_lds[4 * lane];
            const int4 r1 = *(const int4*)&row4col_lds[off2];
            const int rr[8] = {r0.x, r0.y, r0.z, r0.w, r1.x, r1.y, r1.z, r1.w};
            #pragma unroll
            for (int k = 0; k < 8; ++k) {
                const int j = (k < 4) ? 4 * lane + k : 256 + 4 * lane + (k - 4);
                const bool valid = (init_mask >> k) & 1;
                pay_r[k] = valid ? (((unsigned)j << 10) | (unsigned)(rr[k] + 1))
                                 : 0xFFFFFFFFu;
                vwork_r[k] = valid ? v_r[k] : -INFINITY;
                short_r[k] = INFINITY;
                shortfin_r[k] = INFINITY;
                path_r[k] = -1;
            }
        }

        // ---- seed: relax every free row (software-pipelined loads) ----
        {
            int fi = fr_lds[0];
            const float* __restrict__ crow = cb + (size_t)fi * n;
            float4 s0 = *(const float4*)(crow + 4 * lane);
            float4 s1 = *(const float4*)(crow + off2);
            for (int t = 0; t < nfr; ++t) {
                const float4 c0 = s0, c1 = s1;
                const int cur_fi = fi;
                const int tn = (t + 1 < nfr) ? t + 1 : t;
                fi = fr_lds[tn];
                const float* __restrict__ crn = cb + (size_t)fi * n;
                s0 = *(const float4*)(crn + 4 * lane);
                s1 = *(const float4*)(crn + off2);
                const float a = -u_lds[cur_fi];
                #pragma unroll
                for (int k = 0; k < 8; ++k) t_r[k] = a - vwork_r[k];
                const float cvk[8] = {c0.x, c0.y, c0.z, c0.w,
                                      c1.x, c1.y, c1.z, c1.w};
                #pragma unroll
                for (int k = 0; k < 8; ++k) {
                    const float r = cvk[k] + t_r[k];
                    if (r < short_r[k]) { short_r[k] = r; path_r[k] = cur_fi; }
                }
            }
        }

        int sink_j = -1;
        float min_val = 0.0f;
        unsigned sr_mask = 0;
        bool have_cv = false;
        float4 cv0, cv1;
        float a = 0.0f;
        int i_cur = -1;

        for (int pops = 0; pops <= n; ++pops) {
            if (have_cv) {   // relax in-flight expansion row
                #pragma unroll
                for (int k = 0; k < 8; ++k) t_r[k] = a - vwork_r[k];
                {
                    const float c4[4] = {cv0.x, cv0.y, cv0.z, cv0.w};
                    #pragma unroll
                    for (int k = 0; k < 4; ++k) {
                        const float r = c4[k] + t_r[k];
                        if (r < short_r[k]) { short_r[k] = r; path_r[k] = i_cur; }
                    }
                }
                {
                    const float c4[4] = {cv1.x, cv1.y, cv1.z, cv1.w};
                    #pragma unroll
                    for (int k = 0; k < 4; ++k) {
                        const float r = c4[k] + t_r[4 + k];
                        if (r < short_r[4 + k]) { short_r[4 + k] = r; path_r[4 + k] = i_cur; }
                    }
                }
            }

            // fused local argmin tree (prefers lower k = lower j per lane)
            float    m0 = short_r[0], m1 = short_r[1], m2 = short_r[2], m3 = short_r[3];
            float    m4 = short_r[4], m5 = short_r[5], m6 = short_r[6], m7 = short_r[7];
            unsigned q0 = pay_r[0], q1 = pay_r[1], q2 = pay_r[2], q3 = pay_r[3];
            unsigned q4 = pay_r[4], q5 = pay_r[5], q6 = pay_r[6], q7 = pay_r[7];
            pairmin_(m0, q0, m1, q1);  pairmin_(m2, q2, m3, q3);
            pairmin_(m4, q4, m5, q5);  pairmin_(m6, q6, m7, q7);
            pairmin_(m0, q0, m2, q2);  pairmin_(m4, q4, m6, q6);
            pairmin_(m0, q0, m4, q4);
            const float lmin = m0;
            const unsigned lpay = q0;

            // value-only wave min (bit-exact gmin), then ballot-select owner
            const float gmin = wave_min_f32_(lmin);
            const unsigned long long cand = __ballot(lmin == gmin);
            const int wl = (int)__builtin_ctzll(cand);
            const unsigned win = (unsigned)__builtin_amdgcn_readlane((int)lpay, wl);

            min_val = gmin;
            const unsigned jst = win >> 10;
            const unsigned rc1 = win & 0x3FFu;

            // issue next-row loads EARLY (clamped on sink); bookkeeping hides
            const int i_next = (int)rc1 - 1;                 // -1 if sink
            const int i_safe = (i_next < 0) ? 0 : i_next;
            const float* __restrict__ crow2 = cb + (size_t)i_safe * n;
            cv0 = *(const float4*)(crow2 + 4 * lane);
            cv1 = *(const float4*)(crow2 + off2);
            a = gmin - u_lds[i_safe];             // LDS read in load shadow

            // pop bookkeeping: poison winner col on its owner lane
            const int owner = (int)((jst >> 2) & 63u);
            const int kwin  = (int)(((jst >> 8) << 2) | (jst & 3u));
            #pragma unroll
            for (int k = 0; k < 8; ++k) {
                if (k == kwin && lane == owner) {
                    shortfin_r[k] = short_r[k];
                    short_r[k] = INFINITY;
                    vwork_r[k] = -INFINITY;
                }
            }

            if (rc1 == 0u) { sink_j = (int)jst; break; }
            if ((i_next & 63) == lane) sr_mask |= 1u << (i_next >> 6);
            i_cur = i_next;
            have_cv = true;
        }

        if (sink_j < 0) break;   // defensive: should not happen

        // publish final labels/path (vectorized; lanes 61-63's 2nd quad
        // lands in the unread 500..511 pad -> literal offset, NOT off2)
        *(float4*)&shortest_lds[4 * lane] =
            make_float4(shortfin_r[0], shortfin_r[1], shortfin_r[2], shortfin_r[3]);
        *(int4*)&path_lds[4 * lane] =
            make_int4(path_r[0], path_r[1], path_r[2], path_r[3]);
        *(float4*)&shortest_lds[256 + 4 * lane] =
            make_float4(shortfin_r[4], shortfin_r[5], shortfin_r[6], shortfin_r[7]);
        *(int4*)&path_lds[256 + 4 * lane] =
            make_int4(path_r[4], path_r[5], path_r[6], path_r[7]);
        __syncthreads();

        // u-update for scanned matched rows (col4row read BEFORE augmentation)
        #pragma unroll
        for (int k = 0; k < 8; ++k) {
            const int t = lane + (k << 6);
            if (t < n && (sr_mask & (1u << k)))
                u_lds[t] += min_val - shortest_lds[col4row_lds[t]];
        }
        // u-update for ALL sources (dist-0 seeds; includes the origin)
        for (int t = lane; t < nfr; t += 64)
            u_lds[fr_lds[t]] += min_val;
        // v-update for scanned cols (marker: vwork == -INF), register-local
        #pragma unroll
        for (int k = 0; k < 8; ++k) {
            if (((init_mask >> k) & 1) && vwork_r[k] == -INFINITY)
                v_r[k] -= min_val - shortfin_r[k];
        }
        __syncthreads();

        if (lane == 0) {   // augment alternating path; origin = free row hit
            int j = sink_j;
            int origin = -1;
            for (;;) {
                const int ii = path_lds[j];
                row4col_lds[j] = ii;
                const int tmp = col4row_lds[ii];
                col4row_lds[ii] = j;
                if (tmp < 0) { origin = ii; break; }
                j = tmp;
            }
            // swap-remove origin from the free-row list
            const int m = nfr_lds;
            for (int t = 0; t < m; ++t) {
                if (fr_lds[t] == origin) {
                    fr_lds[t] = fr_lds[m - 1];
                    break;
                }
            }
            nfr_lds = m - 1;
        }
        __syncthreads();
    }

    for (int t = lane; t < n; t += 64)
        mapping[b * n + t] = col4row_lds[t];
}

// ---------------------------------------------------------------------------
// Phase 3: extrapolation (square problem => every row assigned; -1 guarded).
// ---------------------------------------------------------------------------
__global__ __launch_bounds__(256) void extrap_boxes_kernel(
    const float* __restrict__ p1_boxes, const float* __restrict__ p2_boxes,
    const float* __restrict__ toffs, const int* __restrict__ mapping,
    float* __restrict__ out_boxes)
{
    const int idx = blockIdx.x * blockDim.x + threadIdx.x;  // b*Mq + i
    if (idx >= Bq * Mq) return;
    const int b = idx / Mq;
    const float t0 = toffs[b * 3 + 0], t1 = toffs[b * 3 + 1], t2 = toffs[b * 3 + 2];
    const float factor = (t2 - t1) / (t1 - t0);
    const int m = mapping[idx];
    const float4 p2 = ((const float4*)p2_boxes)[idx];
    const float4 p1 = (m >= 0) ? ((const float4*)p1_boxes)[b * Nq + m] : p2;
    float4 o;
    o.x = p2.x + (p2.x - p1.x) * factor;
    o.y = p2.y + (p2.y - p1.y) * factor;
    o.z = fmaxf(p2.z + (p2.z - p1.z) * factor, 0.0f);
    o.w = fmaxf(p2.w + (p2.w - p1.w) * factor, 0.0f);
    ((float4*)out_boxes)[idx] = o;
}

__global__ __launch_bounds__(256) void extrap_logits_kernel(
    const float* __restrict__ p1_logits, const float* __restrict__ p2_logits,
    const int* __restrict__ mapping, float* __restrict__ out_logits)
{
    const int idx = blockIdx.x * blockDim.x + threadIdx.x;  // (b*Mq + i)*Cq + c
    if (idx >= Bq * Mq * Cq) return;
    const int c = idx % Cq;
    const int bi = idx / Cq;
    const int b = bi / Mq;
    const int m = mapping[bi];
    const float corr = (m >= 0) ? p1_logits[((size_t)b * Nq + m) * Cq + c] : 0.0f;
    out_logits[idx] = 0.5f * (p2_logits[idx] + corr);
}

// ---------------------------------------------------------------------------
extern "C" void kernel_launch(void* const* d_in, const int* in_sizes, int n_in,
                              void* d_out, int out_size, void* d_ws, size_t ws_size,
                              hipStream_t stream) {
    const float* p1_boxes  = (const float*)d_in[0];  // (B,N,4)
    const float* p1_logits = (const float*)d_in[1];  // (B,N,C)
    const float* p2_boxes  = (const float*)d_in[2];  // (B,M,4)
    const float* p2_logits = (const float*)d_in[3];  // (B,M,C)
    const float* toffs     = (const float*)d_in[4];  // (B,3)
    float* out = (float*)d_out;                      // boxes3 ++ logits3

    char* ws = (char*)d_ws;
    float* cost    = (float*)ws;                                   // 4 MB
    int*   mapping = (int*)  (ws + 4000000);                       // 8 KB
    float* v0      = (float*)(ws + 4008000);                       // 8 KB
    int*   amin    = (int*)  (ws + 4016000);                       // 8 KB
    float* v_auc   = (float*)(ws + 4024000);                       // 8 KB
    int*   owner   = (int*)  (ws + 4032000);                       // 8 KB

    dim3 cgrid((Nq + 15) / 16, (Mq + 15) / 16, Bq);
    cost_kernel<<<cgrid, 256, 0, stream>>>(p1_boxes, p1_logits, p2_boxes, p2_logits, cost);

    colred_kernel<<<dim3(2, Bq), 256, 0, stream>>>(cost, v0, amin);

    auction_kernel<<<Bq, 1024, 0, stream>>>(cost, v0, amin, v_auc, owner);

    lsa_kernel<<<Bq, 64, 0, stream>>>(cost, v_auc, owner, mapping);

    extrap_boxes_kernel<<<(Bq * Mq + 255) / 256, 256, 0, stream>>>(
        p1_boxes, p2_boxes, toffs, mapping, out);
    extrap_logits_kernel<<<(Bq * Mq * Cq + 255) / 256, 256, 0, stream>>>(
        p1_logits, p2_logits, mapping, out + Bq * Mq * 4);
}

// Round 15
// 1899.848 us; speedup vs baseline: 1.2883x; 1.0552x over previous
//
#include <hip/hip_runtime.h>
#include <math.h>

#define Bq 4
#define Mq 500
#define Nq 500
#define Cq 91
#define NPHASE 5
#define KEEP_TOL 1e-6f

// ---------------------------------------------------------------------------
// Phase 1: cost[b,i,j] = 0.5*||center2_i - center1_j||_2
//                      + 0.5*max_c |sigmoid(l2[i,c]) - sigmoid(l1[j,c])|
// ---------------------------------------------------------------------------
__device__ __forceinline__ float sigmoidf_(float x) {
    return 1.0f / (1.0f + expf(-x));
}

__global__ __launch_bounds__(256) void cost_kernel(
    const float* __restrict__ p1_boxes, const float* __restrict__ p1_logits,
    const float* __restrict__ p2_boxes, const float* __restrict__ p2_logits,
    float* __restrict__ cost)
{
    __shared__ float s2t[16][Cq + 1];   // stride 92 -> 2-way bank alias (free)
    __shared__ float s1t[16][Cq + 1];
    __shared__ float b2x[16], b2y[16], b1x[16], b1y[16];
    const int b  = blockIdx.z;
    const int i0 = blockIdx.y * 16;
    const int j0 = blockIdx.x * 16;
    const int tid = threadIdx.x;

    for (int t = tid; t < 16 * Cq; t += 256) {
        const int r = t / Cq, c = t - r * Cq;
        const int i = min(i0 + r, Mq - 1);
        const int j = min(j0 + r, Nq - 1);
        s2t[r][c] = sigmoidf_(p2_logits[((size_t)b * Mq + i) * Cq + c]);
        s1t[r][c] = sigmoidf_(p1_logits[((size_t)b * Nq + j) * Cq + c]);
    }
    if (tid < 16) {
        const int i = min(i0 + tid, Mq - 1);
        const int j = min(j0 + tid, Nq - 1);
        b2x[tid] = p2_boxes[((size_t)b * Mq + i) * 4 + 0];
        b2y[tid] = p2_boxes[((size_t)b * Mq + i) * 4 + 1];
        b1x[tid] = p1_boxes[((size_t)b * Nq + j) * 4 + 0];
        b1y[tid] = p1_boxes[((size_t)b * Nq + j) * 4 + 1];
    }
    __syncthreads();

    const int ty = tid >> 4, tx = tid & 15;
    const int i = i0 + ty, j = j0 + tx;
    if (i < Mq && j < Nq) {
        float mx = 0.0f;
        #pragma unroll 7
        for (int c = 0; c < Cq; ++c)
            mx = fmaxf(mx, fabsf(s2t[ty][c] - s1t[tx][c]));
        const float dx = b2x[ty] - b1x[tx];
        const float dy = b2y[ty] - b1y[tx];
        const float cd = sqrtf(dx * dx + dy * dy);
        cost[((size_t)b * Mq + i) * Nq + j] = 0.5f * cd + 0.5f * mx;
    }
}

// ---------------------------------------------------------------------------
// Phase 1.5: column reduction. v0[b][j] = min_i cost[b][i][j], amin = argmin.
// ---------------------------------------------------------------------------
__global__ __launch_bounds__(256) void colred_kernel(
    const float* __restrict__ cost, float* __restrict__ v0, int* __restrict__ amin)
{
    const int j = blockIdx.x * 256 + threadIdx.x;
    const int b = blockIdx.y;
    if (j >= Nq) return;
    const float* __restrict__ cb = cost + (size_t)b * Mq * Nq;
    float best = INFINITY;
    int bi = 0;
    #pragma unroll 4
    for (int i = 0; i < Mq; ++i) {
        const float c = cb[(size_t)i * Nq + j];
        if (c < best) { best = c; bi = i; }
    }
    v0[b * Nq + j] = best;
    amin[b * Nq + j] = bi;
}

// ---------------------------------------------------------------------------
// Value-only wave64 min: 6 x v_min_f32_dpp (single instr/step) + readlane.
// min over floats (no NaN, no -0 here) is associative => bit-exact gmin.
// ---------------------------------------------------------------------------
template<int CTRL>
__device__ __forceinline__ float dppminv_(float x) {
    const int moved = __builtin_amdgcn_update_dpp(
        0x7F800000, __float_as_int(x), CTRL, 0xF, 0xF, false);
    return fminf(x, __int_as_float(moved));
}
__device__ __forceinline__ float wave_min_f32_(float x) {
    x = dppminv_<0x111>(x);
    x = dppminv_<0x112>(x);
    x = dppminv_<0x114>(x);
    x = dppminv_<0x118>(x);
    x = dppminv_<0x142>(x);
    x = dppminv_<0x143>(x);
    return __int_as_float(__builtin_amdgcn_readlane(__float_as_int(x), 63));
}

// local fused (value,payload) merge — cmp + min + cndmask
__device__ __forceinline__ void pairmin_(float& va, unsigned& pa, float vb, unsigned pb) {
    const bool le = (va <= vb);
    va = fminf(va, vb);
    pa = le ? pa : pb;
}

__device__ __forceinline__ unsigned long long pack_bid_(float p, int row) {
    // p >= 0 -> float bits are order-preserving; row+1 in low word (0 = no bid)
    return ((unsigned long long)__float_as_uint(p) << 32) | (unsigned)(row + 1);
}

// ---------------------------------------------------------------------------
// Phase 1.75: eps-SCALING synchronous auction — R11 config verbatim (best
// measured). Phases bid (g2-g1)+eps, eps {4e-3,8e-4,1.6e-4,3.2e-5,0};
// phase boundary unmatches all rows (prices kept); final eps=0 polish.
// Feasibility: prices only rise => v = v0 - p only falls => c - v >= 0.
// ---------------------------------------------------------------------------
__global__ __launch_bounds__(1024) void auction_kernel(
    const float* __restrict__ cost, const float* __restrict__ v0,
    const int* __restrict__ amin,
    float* __restrict__ v_out, int* __restrict__ owner_out)
{
    constexpr int n = Nq;  // 500
    __shared__ float p_lds[512];
    __shared__ int   owner_lds[512];   // col -> row
    __shared__ int   match_lds[512];   // row -> col
    __shared__ unsigned long long bid_lds[512];
    __shared__ int   flist[512];       // compacted free-row worklist
    __shared__ int   jlist[512];       // columns bid this round (dups ok)
    __shared__ int   nfree_lds, njl_lds;

    const float eps_tab[NPHASE] = {4e-3f, 8e-4f, 1.6e-4f, 3.2e-5f, 0.0f};
    const int   cap_tab[NPHASE] = {48, 32, 32, 32, 64};

    const int tid = threadIdx.x;
    const int lane = tid & 63;
    const int wv = tid >> 6;           // 0..15
    const int b = blockIdx.x;
    const float* __restrict__ cb = cost + (size_t)b * n * n;

    const unsigned init_mask = (lane < 61) ? 0xFFu : 0x0Fu;
    const int off2 = (lane < 61) ? 256 + 4 * lane : 0;

    // v0 cached per lane (constant; effective v = v0 - p)
    float v0_r[8];
    {
        const float4 a0 = *(const float4*)(v0 + b * n + 4 * lane);
        const float4 a1 = *(const float4*)(v0 + b * n + off2);
        const float vv[8] = {a0.x, a0.y, a0.z, a0.w, a1.x, a1.y, a1.z, a1.w};
        #pragma unroll
        for (int k = 0; k < 8; ++k)
            v0_r[k] = ((init_mask >> k) & 1) ? vv[k] : 0.0f;
    }
    if (tid < 512) {
        p_lds[tid] = 0.0f; owner_lds[tid] = -1; match_lds[tid] = -1;
        bid_lds[tid] = 0ull;
    }
    __syncthreads();
    // greedy seed (parallel CAS): col j claims its col-argmin row if free.
    if (tid < n) {
        const int i0 = amin[b * n + tid];
        if (atomicCAS(&match_lds[i0], -1, tid) == -1) owner_lds[tid] = i0;
    }
    __syncthreads();

    for (int ph = 0; ph < NPHASE; ++ph) {
        const float eps = eps_tab[ph];
        const int cap = cap_tab[ph];
        if (ph > 0) {   // phase boundary: unmatch all, KEEP prices
            if (tid < 512) { owner_lds[tid] = -1; match_lds[tid] = -1; }
        }
        __syncthreads();

        for (int round = 0; round < cap; ++round) {
            // ---- compact free-row worklist (every round: fresh) ----
            if (tid == 0) { nfree_lds = 0; njl_lds = 0; }
            __syncthreads();
            if (tid < n && match_lds[tid] < 0)
                flist[atomicAdd(&nfree_lds, 1)] = tid;
            __syncthreads();
            const int nf = nfree_lds;          // uniform after barrier
            if (nf == 0) break;                // phase complete

            // ---- bid phase: one wave per free row ----
            for (int idx = wv; idx < nf; idx += 16) {
                const int i = flist[idx];                 // uniform read
                const float* __restrict__ crow = cb + (size_t)i * n;
                const float4 c0 = *(const float4*)(crow + 4 * lane);
                const float4 c1 = *(const float4*)(crow + off2);
                const float4 p0 = *(const float4*)&p_lds[4 * lane];
                const float4 p1 = *(const float4*)&p_lds[off2];
                const float cc[8] = {c0.x, c0.y, c0.z, c0.w, c1.x, c1.y, c1.z, c1.w};
                const float pp[8] = {p0.x, p0.y, p0.z, p0.w, p1.x, p1.y, p1.z, p1.w};
                float d[8]; unsigned pj[8];
                #pragma unroll
                for (int k = 0; k < 8; ++k) {
                    const int j = (k < 4) ? 4 * lane + k : 256 + 4 * lane + (k - 4);
                    d[k] = ((init_mask >> k) & 1) ? cc[k] - v0_r[k] + pp[k] : INFINITY;
                    pj[k] = (unsigned)j;
                }
                float    a0 = d[0], a1 = d[1], a2 = d[2], a3 = d[3];
                float    a4 = d[4], a5 = d[5], a6 = d[6], a7 = d[7];
                unsigned b0 = pj[0], b1 = pj[1], b2 = pj[2], b3 = pj[3];
                unsigned b4 = pj[4], b5 = pj[5], b6 = pj[6], b7 = pj[7];
                pairmin_(a0, b0, a1, b1);  pairmin_(a2, b2, a3, b3);
                pairmin_(a4, b4, a5, b5);  pairmin_(a6, b6, a7, b7);
                pairmin_(a0, b0, a2, b2);  pairmin_(a4, b4, a6, b6);
                pairmin_(a0, b0, a4, b4);
                const float lmin = a0;
                const unsigned lpay = b0;

                const float g1 = wave_min_f32_(lmin);
                const unsigned long long cm = __ballot(lmin == g1);
                const int wl = (int)__builtin_ctzll(cm);
                const int j1 = __builtin_amdgcn_readlane((int)lpay, wl);

                // second-best: poison j1 on its owner lane, value-only re-reduce
                const int ow = (j1 >> 2) & 63, kw = ((j1 >> 8) << 2) | (j1 & 3);
                float lmin2 = INFINITY;
                #pragma unroll
                for (int k = 0; k < 8; ++k) {
                    const float dv = (k == kw && lane == ow) ? INFINITY : d[k];
                    lmin2 = fminf(lmin2, dv);
                }
                const float g2 = wave_min_f32_(lmin2);

                if (lane == 0) {
                    const float pnew = p_lds[j1] + (g2 - g1) + eps;
                    atomicMax(&bid_lds[j1], pack_bid_(pnew, i));
                    jlist[atomicAdd(&njl_lds, 1)] = j1;
                }
            }
            __syncthreads();

            // ---- assignment: only the columns that received bids ----
            const int nj = njl_lds;
            for (int t = tid; t < nj; t += 1024) {
                const int j = jlist[t];
                const unsigned long long bd = atomicExch(&bid_lds[j], 0ull);
                if (bd != 0ull) {      // dups see 0 after first exchange
                    const int ri = (int)(bd & 0xFFFFFFFFull) - 1;
                    const float pn = __uint_as_float((unsigned)(bd >> 32));
                    const int prev = owner_lds[j];
                    if (prev >= 0) match_lds[prev] = -1;   // evictee didn't bid
                    owner_lds[j] = ri;
                    match_lds[ri] = j;
                    p_lds[j] = pn;
                }
            }
            __syncthreads();
        }
    }

    if (tid < n) {
        v_out[b * n + tid] = v0[b * n + tid] - p_lds[tid];
        owner_out[b * n + tid] = owner_lds[tid];
    }
}

// ---------------------------------------------------------------------------
// Phase 2: exact LAP finisher — R14's multi-source SSP verbatim, with the
// R15 TOLERANCE-KEEP transfer. Diagnosis (R7-R14 arc): polish-committed
// contested edges end INDIFFERENT (rc1 == mu within cross-arithmetic noise
// <= ~5e-7: transfer computes c-(v0-p), auction computed (c-v0)+p), so the
// strict keep-check coin-flipped ~half of them into serial SSP (~17us/row)
// — that WAS the F~80 tail. Fix:
//   keep if rc1 <= mu + 1e-6  (2x the noise band);
//   v[j1] = min(v_old, c - mu)  — never-raise-v guard: for normal rows
//   (rc1 <= mu) bit-identical to before; for rescued rows v is UNCHANGED,
//   so duals remain exactly feasible (c-u-v >= 0 everywhere preserved).
// A rescued matched edge carries slack <= 1e-6 instead of 0: SSP paths
// using its reverse arc are OVERcounted by <= 1e-6 (never negative =>
// Dijkstra valid, feasibility exact). The matching can deviate from the
// true optimum only if the uniqueness gap < ~1e-6 — below the float noise
// this instance has absorbed across 14 trajectories, all absmax 0.0.
// ---------------------------------------------------------------------------
__global__ __launch_bounds__(64) void lsa_kernel(
    const float* __restrict__ cost, const float* __restrict__ v_in,
    const int* __restrict__ owner_in, int* __restrict__ mapping)
{
    constexpr int n = Nq;  // 500
    __shared__ float u_lds[512];
    __shared__ float shortest_lds[512];
    __shared__ int   path_lds[512];
    __shared__ int   row4col_lds[512];
    __shared__ int   col4row_lds[512];
    __shared__ int   fr_lds[512];      // free-row list
    __shared__ int   nfr_lds;

    const int lane = threadIdx.x;
    const int b = blockIdx.x;
    const float* __restrict__ cb = cost + (size_t)b * n * n;

    // k<4 -> j = 4*lane+k ; k>=4 -> j = 256+4*lane+(k-4)
    const unsigned init_mask = (lane < 61) ? 0xFFu : 0x0Fu;
    const int off2 = (lane < 61) ? 256 + 4 * lane : 0;   // clamped 2nd-quad offset

    float v_r[8], vwork_r[8], short_r[8], shortfin_r[8], t_r[8];
    int path_r[8];
    unsigned pay_r[8];   // (j<<10) | (row4col[j]+1)

    // --- duals + matching from the auction pre-pass ---
    {
        const float4 a0 = *(const float4*)(v_in + b * n + 4 * lane);
        const float4 a1 = *(const float4*)(v_in + b * n + off2);
        const float vv[8] = {a0.x, a0.y, a0.z, a0.w, a1.x, a1.y, a1.z, a1.w};
        #pragma unroll
        for (int k = 0; k < 8; ++k)
            v_r[k] = ((init_mask >> k) & 1) ? vv[k] : 0.0f;
    }
    for (int t = lane; t < 512; t += 64) {
        u_lds[t] = 0.0f; row4col_lds[t] = -1; col4row_lds[t] = -1;
    }
    __syncthreads();
    for (int t = lane; t < n; t += 64) {
        const int r = owner_in[b * n + t];
        if (r >= 0 && atomicCAS(&col4row_lds[r], -1, t) == -1)
            row4col_lds[t] = r;    // mutual consistency guaranteed
    }
    __syncthreads();

    // --- JV reduction transfer (tolerance-keep, never-raise-v), pipelined ---
    {
        int j1c = col4row_lds[0];
        float4 ta0 = *(const float4*)(cb + 4 * lane);
        float4 ta1 = *(const float4*)(cb + off2);
        for (int i2 = 0; i2 < n; ++i2) {
            const float4 c0 = ta0, c1 = ta1;
            const int j1 = j1c;
            const int inx = (i2 + 1 < n) ? i2 + 1 : i2;
            const float* __restrict__ crn = cb + (size_t)inx * n;
            ta0 = *(const float4*)(crn + 4 * lane);
            ta1 = *(const float4*)(crn + off2);
            j1c = col4row_lds[inx];
            if (j1 < 0) continue;                  // free row: no transfer
            const float cc[8] = {c0.x, c0.y, c0.z, c0.w, c1.x, c1.y, c1.z, c1.w};
            const int owner = (j1 >> 2) & 63;      // wave-uniform
            const int kwin  = ((j1 >> 8) << 2) | (j1 & 3);
            float d[8];
            float rcj = INFINITY;                  // reduced cost at j1 (owner lane)
            #pragma unroll
            for (int k = 0; k < 8; ++k) {
                const bool mine = (k == kwin && lane == owner);
                const bool use = ((init_mask >> k) & 1) && !mine;
                d[k] = use ? cc[k] - v_r[k] : INFINITY;
                if (mine) rcj = cc[k] - v_r[k];
            }
            const float mu = wave_min_f32_(
                fminf(fminf(fminf(d[0], d[1]), fminf(d[2], d[3])),
                      fminf(fminf(d[4], d[5]), fminf(d[6], d[7]))));
            const float rc1g = __int_as_float(
                __builtin_amdgcn_readlane(__float_as_int(rcj), owner));
            const bool keep = (rc1g <= mu + KEEP_TOL);   // tolerance keep
            #pragma unroll
            for (int k = 0; k < 8; ++k)
                if (keep && k == kwin && lane == owner)
                    v_r[k] = fminf(v_r[k], cc[k] - mu);  // never raise v
            if (lane == 0) {
                if (keep) u_lds[i2] = mu;
                else { row4col_lds[j1] = -1; col4row_lds[i2] = -1; }  // free row
            }
        }
    }
    __syncthreads();

    // --- build free-row list ---
    if (lane == 0) nfr_lds = 0;
    __syncthreads();
    for (int t = lane; t < n; t += 64)
        if (col4row_lds[t] < 0) fr_lds[atomicAdd(&nfr_lds, 1)] = t;
    __syncthreads();

    // --- multi-source successive shortest paths (R14, proven-neutral) ---
    for (int aug = 0; aug < n; ++aug) {
        const int nfr = nfr_lds;       // uniform after barrier
        if (nfr == 0) break;

        // per-augment state reset (payloads from current matching)
        {
            const int4 r0 = *(const int4*)&row4col_lds[4 * lane];
            const int4 r1 = *(const int4*)&row4col_lds[off2];
            const int rr[8] = {r0.x, r0.y, r0.z, r0.w, r1.x, r1.y, r1.z, r1.w};
            #pragma unroll
            for (int k = 0; k < 8; ++k) {
                const int j = (k < 4) ? 4 * lane + k : 256 + 4 * lane + (k - 4);
                const bool valid = (init_mask >> k) & 1;
                pay_r[k] = valid ? (((unsigned)j << 10) | (unsigned)(rr[k] + 1))
                                 : 0xFFFFFFFFu;
                vwork_r[k] = valid ? v_r[k] : -INFINITY;
                short_r[k] = INFINITY;
                shortfin_r[k] = INFINITY;
                path_r[k] = -1;
            }
        }

        // ---- seed: relax every free row (software-pipelined loads) ----
        {
            int fi = fr_lds[0];
            const float* __restrict__ crow = cb + (size_t)fi * n;
            float4 s0 = *(const float4*)(crow + 4 * lane);
            float4 s1 = *(const float4*)(crow + off2);
            for (int t = 0; t < nfr; ++t) {
                const float4 c0 = s0, c1 = s1;
                const int cur_fi = fi;
                const int tn = (t + 1 < nfr) ? t + 1 : t;
                fi = fr_lds[tn];
                const float* __restrict__ crn = cb + (size_t)fi * n;
                s0 = *(const float4*)(crn + 4 * lane);
                s1 = *(const float4*)(crn + off2);
                const float a = -u_lds[cur_fi];
                #pragma unroll
                for (int k = 0; k < 8; ++k) t_r[k] = a - vwork_r[k];
                const float cvk[8] = {c0.x, c0.y, c0.z, c0.w,
                                      c1.x, c1.y, c1.z, c1.w};
                #pragma unroll
                for (int k = 0; k < 8; ++k) {
                    const float r = cvk[k] + t_r[k];
                    if (r < short_r[k]) { short_r[k] = r; path_r[k] = cur_fi; }
                }
            }
        }

        int sink_j = -1;
        float min_val = 0.0f;
        unsigned sr_mask = 0;
        bool have_cv = false;
        float4 cv0, cv1;
        float a = 0.0f;
        int i_cur = -1;

        for (int pops = 0; pops <= n; ++pops) {
            if (have_cv) {   // relax in-flight expansion row
                #pragma unroll
                for (int k = 0; k < 8; ++k) t_r[k] = a - vwork_r[k];
                {
                    const float c4[4] = {cv0.x, cv0.y, cv0.z, cv0.w};
                    #pragma unroll
                    for (int k = 0; k < 4; ++k) {
                        const float r = c4[k] + t_r[k];
                        if (r < short_r[k]) { short_r[k] = r; path_r[k] = i_cur; }
                    }
                }
                {
                    const float c4[4] = {cv1.x, cv1.y, cv1.z, cv1.w};
                    #pragma unroll
                    for (int k = 0; k < 4; ++k) {
                        const float r = c4[k] + t_r[4 + k];
                        if (r < short_r[4 + k]) { short_r[4 + k] = r; path_r[4 + k] = i_cur; }
                    }
                }
            }

            // fused local argmin tree (prefers lower k = lower j per lane)
            float    m0 = short_r[0], m1 = short_r[1], m2 = short_r[2], m3 = short_r[3];
            float    m4 = short_r[4], m5 = short_r[5], m6 = short_r[6], m7 = short_r[7];
            unsigned q0 = pay_r[0], q1 = pay_r[1], q2 = pay_r[2], q3 = pay_r[3];
            unsigned q4 = pay_r[4], q5 = pay_r[5], q6 = pay_r[6], q7 = pay_r[7];
            pairmin_(m0, q0, m1, q1);  pairmin_(m2, q2, m3, q3);
            pairmin_(m4, q4, m5, q5);  pairmin_(m6, q6, m7, q7);
            pairmin_(m0, q0, m2, q2);  pairmin_(m4, q4, m6, q6);
            pairmin_(m0, q0, m4, q4);
            const float lmin = m0;
            const unsigned lpay = q0;

            // value-only wave min (bit-exact gmin), then ballot-select owner
            const float gmin = wave_min_f32_(lmin);
            const unsigned long long cand = __ballot(lmin == gmin);
            const int wl = (int)__builtin_ctzll(cand);
            const unsigned win = (unsigned)__builtin_amdgcn_readlane((int)lpay, wl);

            min_val = gmin;
            const unsigned jst = win >> 10;
            const unsigned rc1 = win & 0x3FFu;

            // issue next-row loads EARLY (clamped on sink); bookkeeping hides
            const int i_next = (int)rc1 - 1;                 // -1 if sink
            const int i_safe = (i_next < 0) ? 0 : i_next;
            const float* __restrict__ crow2 = cb + (size_t)i_safe * n;
            cv0 = *(const float4*)(crow2 + 4 * lane);
            cv1 = *(const float4*)(crow2 + off2);
            a = gmin - u_lds[i_safe];             // LDS read in load shadow

            // pop bookkeeping: poison winner col on its owner lane
            const int owner = (int)((jst >> 2) & 63u);
            const int kwin  = (int)(((jst >> 8) << 2) | (jst & 3u));
            #pragma unroll
            for (int k = 0; k < 8; ++k) {
                if (k == kwin && lane == owner) {
                    shortfin_r[k] = short_r[k];
                    short_r[k] = INFINITY;
                    vwork_r[k] = -INFINITY;
                }
            }

            if (rc1 == 0u) { sink_j = (int)jst; break; }
            if ((i_next & 63) == lane) sr_mask |= 1u << (i_next >> 6);
            i_cur = i_next;
            have_cv = true;
        }

        if (sink_j < 0) break;   // defensive: should not happen

        // publish final labels/path (vectorized; lanes 61-63's 2nd quad
        // lands in the unread 500..511 pad -> literal offset, NOT off2)
        *(float4*)&shortest_lds[4 * lane] =
            make_float4(shortfin_r[0], shortfin_r[1], shortfin_r[2], shortfin_r[3]);
        *(int4*)&path_lds[4 * lane] =
            make_int4(path_r[0], path_r[1], path_r[2], path_r[3]);
        *(float4*)&shortest_lds[256 + 4 * lane] =
            make_float4(shortfin_r[4], shortfin_r[5], shortfin_r[6], shortfin_r[7]);
        *(int4*)&path_lds[256 + 4 * lane] =
            make_int4(path_r[4], path_r[5], path_r[6], path_r[7]);
        __syncthreads();

        // u-update for scanned matched rows (col4row read BEFORE augmentation)
        #pragma unroll
        for (int k = 0; k < 8; ++k) {
            const int t = lane + (k << 6);
            if (t < n && (sr_mask & (1u << k)))
                u_lds[t] += min_val - shortest_lds[col4row_lds[t]];
        }
        // u-update for ALL sources (dist-0 seeds; includes the origin)
        for (int t = lane; t < nfr; t += 64)
            u_lds[fr_lds[t]] += min_val;
        // v-update for scanned cols (marker: vwork == -INF), register-local
        #pragma unroll
        for (int k = 0; k < 8; ++k) {
            if (((init_mask >> k) & 1) && vwork_r[k] == -INFINITY)
                v_r[k] -= min_val - shortfin_r[k];
        }
        __syncthreads();

        if (lane == 0) {   // augment alternating path; origin = free row hit
            int j = sink_j;
            int origin = -1;
            for (;;) {
                const int ii = path_lds[j];
                row4col_lds[j] = ii;
                const int tmp = col4row_lds[ii];
                col4row_lds[ii] = j;
                if (tmp < 0) { origin = ii; break; }
                j = tmp;
            }
            // swap-remove origin from the free-row list
            const int m = nfr_lds;
            for (int t = 0; t < m; ++t) {
                if (fr_lds[t] == origin) {
                    fr_lds[t] = fr_lds[m - 1];
                    break;
                }
            }
            nfr_lds = m - 1;
        }
        __syncthreads();
    }

    for (int t = lane; t < n; t += 64)
        mapping[b * n + t] = col4row_lds[t];
}

// ---------------------------------------------------------------------------
// Phase 3: extrapolation (square problem => every row assigned; -1 guarded).
// ---------------------------------------------------------------------------
__global__ __launch_bounds__(256) void extrap_boxes_kernel(
    const float* __restrict__ p1_boxes, const float* __restrict__ p2_boxes,
    const float* __restrict__ toffs, const int* __restrict__ mapping,
    float* __restrict__ out_boxes)
{
    const int idx = blockIdx.x * blockDim.x + threadIdx.x;  // b*Mq + i
    if (idx >= Bq * Mq) return;
    const int b = idx / Mq;
    const float t0 = toffs[b * 3 + 0], t1 = toffs[b * 3 + 1], t2 = toffs[b * 3 + 2];
    const float factor = (t2 - t1) / (t1 - t0);
    const int m = mapping[idx];
    const float4 p2 = ((const float4*)p2_boxes)[idx];
    const float4 p1 = (m >= 0) ? ((const float4*)p1_boxes)[b * Nq + m] : p2;
    float4 o;
    o.x = p2.x + (p2.x - p1.x) * factor;
    o.y = p2.y + (p2.y - p1.y) * factor;
    o.z = fmaxf(p2.z + (p2.z - p1.z) * factor, 0.0f);
    o.w = fmaxf(p2.w + (p2.w - p1.w) * factor, 0.0f);
    ((float4*)out_boxes)[idx] = o;
}

__global__ __launch_bounds__(256) void extrap_logits_kernel(
    const float* __restrict__ p1_logits, const float* __restrict__ p2_logits,
    const int* __restrict__ mapping, float* __restrict__ out_logits)
{
    const int idx = blockIdx.x * blockDim.x + threadIdx.x;  // (b*Mq + i)*Cq + c
    if (idx >= Bq * Mq * Cq) return;
    const int c = idx % Cq;
    const int bi = idx / Cq;
    const int b = bi / Mq;
    const int m = mapping[bi];
    const float corr = (m >= 0) ? p1_logits[((size_t)b * Nq + m) * Cq + c] : 0.0f;
    out_logits[idx] = 0.5f * (p2_logits[idx] + corr);
}

// ---------------------------------------------------------------------------
extern "C" void kernel_launch(void* const* d_in, const int* in_sizes, int n_in,
                              void* d_out, int out_size, void* d_ws, size_t ws_size,
                              hipStream_t stream) {
    const float* p1_boxes  = (const float*)d_in[0];  // (B,N,4)
    const float* p1_logits = (const float*)d_in[1];  // (B,N,C)
    const float* p2_boxes  = (const float*)d_in[2];  // (B,M,4)
    const float* p2_logits = (const float*)d_in[3];  // (B,M,C)
    const float* toffs     = (const float*)d_in[4];  // (B,3)
    float* out = (float*)d_out;                      // boxes3 ++ logits3

    char* ws = (char*)d_ws;
    float* cost    = (float*)ws;                                   // 4 MB
    int*   mapping = (int*)  (ws + 4000000);                       // 8 KB
    float* v0      = (float*)(ws + 4008000);                       // 8 KB
    int*   amin    = (int*)  (ws + 4016000);                       // 8 KB
    float* v_auc   = (float*)(ws + 4024000);                       // 8 KB
    int*   owner   = (int*)  (ws + 4032000);                       // 8 KB

    dim3 cgrid((Nq + 15) / 16, (Mq + 15) / 16, Bq);
    cost_kernel<<<cgrid, 256, 0, stream>>>(p1_boxes, p1_logits, p2_boxes, p2_logits, cost);

    colred_kernel<<<dim3(2, Bq), 256, 0, stream>>>(cost, v0, amin);

    auction_kernel<<<Bq, 1024, 0, stream>>>(cost, v0, amin, v_auc, owner);

    lsa_kernel<<<Bq, 64, 0, stream>>>(cost, v_auc, owner, mapping);

    extrap_boxes_kernel<<<(Bq * Mq + 255) / 256, 256, 0, stream>>>(
        p1_boxes, p2_boxes, toffs, mapping, out);
    extrap_logits_kernel<<<(Bq * Mq * Cq + 255) / 256, 256, 0, stream>>>(
        p1_logits, p2_logits, mapping, out + Bq * Mq * 4);
}